// Round 1
// baseline (253.567 us; speedup 1.0000x reference)
//
#include <hip/hip_runtime.h>

// SSIM loss, fused single-pass: vertical 7-row sliding sums in registers,
// horizontal 7-tap sums via LDS, global mean via block-reduce + atomicAdd.
//
// X, Y: [32,3,512,512] f32 -> treat as 96 images of 512x512.
// Output: scalar f32 = 1 - mean(S) over [96,506,506].

#define WIN   7
#define IW    512
#define IH    512
#define OUTW  506
#define OUTH  506
#define BAND  63          // output rows per block (multiple of 7)
#define NBANDS 9          // ceil(506/63)
#define NIMG  96
#define SSIM_C1 1e-4f
#define SSIM_C2 9e-4f
#define INV_NP  (1.0f/49.0f)
#define COV_NORM (49.0f/48.0f)
#define TOTAL_OUT 24579456.0f   // 96*506*506

__device__ __forceinline__ float ssim_val(float Sx, float Sy, float Sxx,
                                          float Syy, float Sxy) {
    float ux  = Sx  * INV_NP, uy  = Sy  * INV_NP;
    float uxx = Sxx * INV_NP, uyy = Syy * INV_NP, uxy = Sxy * INV_NP;
    float vx  = COV_NORM * (uxx - ux * ux);
    float vy  = COV_NORM * (uyy - uy * uy);
    float vxy = COV_NORM * (uxy - ux * uy);
    float A1 = 2.0f * ux * uy + SSIM_C1;
    float A2 = 2.0f * vxy + SSIM_C2;
    float B1 = ux * ux + uy * uy + SSIM_C1;
    float B2 = vx + vy + SSIM_C2;
    return (A1 * A2) / (B1 * B2);
}

__global__ void ssim_zero(float* acc) {
    if (threadIdx.x == 0) acc[0] = 0.0f;
}

__global__ __launch_bounds__(256) void ssim_main(const float* __restrict__ X,
                                                 const float* __restrict__ Y,
                                                 float* __restrict__ acc) {
    __shared__ float lsx[IW], lsy[IW], lsxx[IW], lsyy[IW], lsxy[IW];
    const int t    = threadIdx.x;
    const int band = blockIdx.x;
    const int img  = blockIdx.y;
    const int r0   = band * BAND;
    const float* Xi = X + (size_t)img * IH * IW;
    const float* Yi = Y + (size_t)img * IH * IW;
    const int c0 = t, c1 = t + 256;

    // 7-row ring buffers (static indices after unroll) + running vertical sums
    float rx0[7], ry0[7], rx1[7], ry1[7];
    float sx0 = 0, sy0 = 0, sxx0 = 0, syy0 = 0, sxy0 = 0;
    float sx1 = 0, sy1 = 0, sxx1 = 0, syy1 = 0, sxy1 = 0;

    // prime with 6 rows: input rows r0 .. r0+5
#pragma unroll
    for (int i = 0; i < 6; ++i) {
        int ri = r0 + i;
        float x0 = Xi[ri * IW + c0], y0 = Yi[ri * IW + c0];
        float x1 = Xi[ri * IW + c1], y1 = Yi[ri * IW + c1];
        rx0[i] = x0; ry0[i] = y0; rx1[i] = x1; ry1[i] = y1;
        sx0 += x0; sy0 += y0; sxx0 += x0 * x0; syy0 += y0 * y0; sxy0 += x0 * y0;
        sx1 += x1; sy1 += y1; sxx1 += x1 * x1; syy1 += y1 * y1; sxy1 += x1 * y1;
    }

    float accS = 0.0f;
    int j = 0;
    bool done = false;
    for (int b7 = 0; b7 < BAND / 7; ++b7) {
#pragma unroll
        for (int u = 0; u < 7; ++u, ++j) {
            int r = r0 + j;                 // uniform across block
            if (r >= OUTH) { done = true; break; }
            int ri = r + 6;                 // new input row; always < 512
            const int sn = (u + 6) % 7;     // static ring slot after unroll

            float x0 = Xi[ri * IW + c0], y0 = Yi[ri * IW + c0];
            float x1 = Xi[ri * IW + c1], y1 = Yi[ri * IW + c1];
            sx0 += x0; sy0 += y0; sxx0 += x0 * x0; syy0 += y0 * y0; sxy0 += x0 * y0;
            sx1 += x1; sy1 += y1; sxx1 += x1 * x1; syy1 += y1 * y1; sxy1 += x1 * y1;
            rx0[sn] = x0; ry0[sn] = y0; rx1[sn] = x1; ry1[sn] = y1;

            __syncthreads();   // previous iteration's LDS reads complete
            lsx[c0] = sx0; lsy[c0] = sy0; lsxx[c0] = sxx0; lsyy[c0] = syy0; lsxy[c0] = sxy0;
            lsx[c1] = sx1; lsy[c1] = sy1; lsxx[c1] = sxx1; lsyy[c1] = syy1; lsxy[c1] = sxy1;
            __syncthreads();   // writes visible

            if (t < 253) {     // 253*2 = 506 output columns
                int oc = 2 * t;
                float aSx = 0, aSy = 0, aSxx = 0, aSyy = 0, aSxy = 0;
#pragma unroll
                for (int k = 0; k < 7; ++k) {
                    aSx  += lsx [oc + k];
                    aSy  += lsy [oc + k];
                    aSxx += lsxx[oc + k];
                    aSyy += lsyy[oc + k];
                    aSxy += lsxy[oc + k];
                }
                accS += ssim_val(aSx, aSy, aSxx, aSyy, aSxy);
                // slide by one column
                float bSx  = aSx  - lsx [oc] + lsx [oc + 7];
                float bSy  = aSy  - lsy [oc] + lsy [oc + 7];
                float bSxx = aSxx - lsxx[oc] + lsxx[oc + 7];
                float bSyy = aSyy - lsyy[oc] + lsyy[oc + 7];
                float bSxy = aSxy - lsxy[oc] + lsxy[oc + 7];
                accS += ssim_val(bSx, bSy, bSxx, bSyy, bSxy);
            }

            // retire oldest row (slot u) from vertical sums
            float xo = rx0[u], yo = ry0[u];
            sx0 -= xo; sy0 -= yo; sxx0 -= xo * xo; syy0 -= yo * yo; sxy0 -= xo * yo;
            xo = rx1[u]; yo = ry1[u];
            sx1 -= xo; sy1 -= yo; sxx1 -= xo * xo; syy1 -= yo * yo; sxy1 -= xo * yo;
        }
        if (done) break;
    }

    // block reduction: wave shuffle then LDS
    for (int off = 32; off > 0; off >>= 1)
        accS += __shfl_down(accS, off, 64);
    __shared__ float wsum[4];
    if ((t & 63) == 0) wsum[t >> 6] = accS;
    __syncthreads();
    if (t == 0) atomicAdd(acc, wsum[0] + wsum[1] + wsum[2] + wsum[3]);
}

__global__ void ssim_finalize(const float* __restrict__ acc,
                              float* __restrict__ out) {
    if (threadIdx.x == 0) out[0] = 1.0f - acc[0] / TOTAL_OUT;
}

extern "C" void kernel_launch(void* const* d_in, const int* in_sizes, int n_in,
                              void* d_out, int out_size, void* d_ws, size_t ws_size,
                              hipStream_t stream) {
    const float* X = (const float*)d_in[0];
    const float* Y = (const float*)d_in[1];
    float* acc = (float*)d_ws;    // 1 float of scratch; re-poisoned each call
    float* out = (float*)d_out;

    hipLaunchKernelGGL(ssim_zero, dim3(1), dim3(64), 0, stream, acc);
    hipLaunchKernelGGL(ssim_main, dim3(NBANDS, NIMG), dim3(256), 0, stream,
                       X, Y, acc);
    hipLaunchKernelGGL(ssim_finalize, dim3(1), dim3(64), 0, stream, acc, out);
}

// Round 2
// 248.524 us; speedup vs baseline: 1.0203x; 1.0203x over previous
//
#include <hip/hip_runtime.h>

// SSIM loss, fused. Round 2: LDS-issue-minimized structure.
//  - 128 threads/block; thread owns 4 consecutive columns (float4 global loads).
//  - Vertical 7-row sliding column sums in registers; old row retired by
//    re-reading from global (L1/L2-hot, 28 KB/block window).
//  - Column sums -> LDS in swizzled stride-12 layout: word(col)=12*(col>>3)+(col&7).
//    Makes both b128 writes (2 lanes/bank -> free) and b128 strip reads
//    (8 lanes/bank = b128 baseline) conflict-free.
//  - Horizontal: 2 output rows/iter, wave w takes row r+w; lane s produces
//    8 output cols (8s..8s+7) via register sliding window from 14 col sums
//    read as 3x ds_read_b128 + 1x ds_read_b64 per quantity.
//  - SSIM evaluated on raw sums (scale factors cancel), v_rcp for the divide.

#define IW    512
#define OUTW  506
#define OUTH  506
#define BAND  46          // output rows per block; 46*11 = 506 exactly
#define NBANDS 11
#define NIMG  96
#define C1N2  0.2401f     // 1e-4 * 49^2
#define C2N2  2.1609f     // 9e-4 * 49^2
#define KA    (49.0f/24.0f)
#define KB    (49.0f/48.0f)
#define TOTAL_OUT 24579456.0f   // 96*506*506

__global__ void ssim_zero(float* acc) {
    if (threadIdx.x == 0) acc[0] = 0.0f;
}

__global__ __launch_bounds__(128) void ssim_main(const float* __restrict__ X,
                                                 const float* __restrict__ Y,
                                                 float* __restrict__ acc) {
    // [2 rows][5 quantities][65 slots * 12 words]; slot 64 read-only garbage
    // for lane 63's halo (its cols >= 506 are masked).
    __shared__ float plane[2][5][65 * 12];

    const int t    = threadIdx.x;
    const int band = blockIdx.x;
    const int img  = blockIdx.y;
    const int r0   = band * BAND;
    const float4* X4 = (const float4*)(X + (size_t)img * IW * IW);
    const float4* Y4 = (const float4*)(Y + (size_t)img * IW * IW);
    // thread owns cols 4t..4t+3 ; row stride in float4 units = 128

    float4 s0 = {0,0,0,0}, s1 = {0,0,0,0}, s2 = {0,0,0,0},
           s3 = {0,0,0,0}, s4 = {0,0,0,0};

    // prime with input rows r0 .. r0+5
#pragma unroll
    for (int i = 0; i < 6; ++i) {
        float4 x = X4[(r0 + i) * 128 + t];
        float4 y = Y4[(r0 + i) * 128 + t];
        s0.x += x.x; s0.y += x.y; s0.z += x.z; s0.w += x.w;
        s1.x += y.x; s1.y += y.y; s1.z += y.z; s1.w += y.w;
        s2.x = fmaf(x.x,x.x,s2.x); s2.y = fmaf(x.y,x.y,s2.y);
        s2.z = fmaf(x.z,x.z,s2.z); s2.w = fmaf(x.w,x.w,s2.w);
        s3.x = fmaf(y.x,y.x,s3.x); s3.y = fmaf(y.y,y.y,s3.y);
        s3.z = fmaf(y.z,y.z,s3.z); s3.w = fmaf(y.w,y.w,s3.w);
        s4.x = fmaf(x.x,y.x,s4.x); s4.y = fmaf(x.y,y.y,s4.y);
        s4.z = fmaf(x.z,y.z,s4.z); s4.w = fmaf(x.w,y.w,s4.w);
    }

    const int wslot = 12 * (t >> 1) + 4 * (t & 1);  // float4-aligned word offset
    const int wv = t >> 6;   // wave id (0,1)
    const int s  = t & 63;   // lane
    float accS = 0.0f;

    for (int j = 0; j < BAND; j += 2) {
#pragma unroll
        for (int k = 0; k < 2; ++k) {
            const int rr = r0 + j + k;          // output row
            // add new input row rr+6
            float4 x = X4[(rr + 6) * 128 + t];
            float4 y = Y4[(rr + 6) * 128 + t];
            s0.x += x.x; s0.y += x.y; s0.z += x.z; s0.w += x.w;
            s1.x += y.x; s1.y += y.y; s1.z += y.z; s1.w += y.w;
            s2.x = fmaf(x.x,x.x,s2.x); s2.y = fmaf(x.y,x.y,s2.y);
            s2.z = fmaf(x.z,x.z,s2.z); s2.w = fmaf(x.w,x.w,s2.w);
            s3.x = fmaf(y.x,y.x,s3.x); s3.y = fmaf(y.y,y.y,s3.y);
            s3.z = fmaf(y.z,y.z,s3.z); s3.w = fmaf(y.w,y.w,s3.w);
            s4.x = fmaf(x.x,y.x,s4.x); s4.y = fmaf(x.y,y.y,s4.y);
            s4.z = fmaf(x.z,y.z,s4.z); s4.w = fmaf(x.w,y.w,s4.w);
            // publish column sums (rows rr..rr+6) for this subrow
            *(float4*)&plane[k][0][wslot] = s0;
            *(float4*)&plane[k][1][wslot] = s1;
            *(float4*)&plane[k][2][wslot] = s2;
            *(float4*)&plane[k][3][wslot] = s3;
            *(float4*)&plane[k][4][wslot] = s4;
            // retire input row rr (re-read; L1/L2-hot)
            float4 ox = X4[rr * 128 + t];
            float4 oy = Y4[rr * 128 + t];
            s0.x -= ox.x; s0.y -= ox.y; s0.z -= ox.z; s0.w -= ox.w;
            s1.x -= oy.x; s1.y -= oy.y; s1.z -= oy.z; s1.w -= oy.w;
            s2.x = fmaf(-ox.x,ox.x,s2.x); s2.y = fmaf(-ox.y,ox.y,s2.y);
            s2.z = fmaf(-ox.z,ox.z,s2.z); s2.w = fmaf(-ox.w,ox.w,s2.w);
            s3.x = fmaf(-oy.x,oy.x,s3.x); s3.y = fmaf(-oy.y,oy.y,s3.y);
            s3.z = fmaf(-oy.z,oy.z,s3.z); s3.w = fmaf(-oy.w,oy.w,s3.w);
            s4.x = fmaf(-ox.x,oy.x,s4.x); s4.y = fmaf(-ox.y,oy.y,s4.y);
            s4.z = fmaf(-ox.z,oy.z,s4.z); s4.w = fmaf(-ox.w,oy.w,s4.w);
        }
        __syncthreads();   // column sums visible

        // horizontal: wave wv handles output row r0+j+wv; lane s -> cols 8s..8s+7
        float W[5][8];
#pragma unroll
        for (int q = 0; q < 5; ++q) {
            const float* pl = plane[wv][q];
            float4 a = *(const float4*)(pl + 12 * s);
            float4 b = *(const float4*)(pl + 12 * s + 4);
            float4 cc = *(const float4*)(pl + 12 * (s + 1));
            float2 dd = *(const float2*)(pl + 12 * (s + 1) + 4);
            float c[14] = {a.x, a.y, a.z, a.w, b.x, b.y, b.z, b.w,
                           cc.x, cc.y, cc.z, cc.w, dd.x, dd.y};
            float Wv = ((c[0] + c[1]) + (c[2] + c[3])) +
                       ((c[4] + c[5]) + c[6]);
            W[q][0] = Wv;
#pragma unroll
            for (int m = 1; m < 8; ++m) {
                Wv += c[m + 6] - c[m - 1];
                W[q][m] = Wv;
            }
        }
#pragma unroll
        for (int m = 0; m < 8; ++m) {
            float Sx = W[0][m], Sy = W[1][m];
            float Sxx = W[2][m], Syy = W[3][m], Sxy = W[4][m];
            float sxsy = Sx * Sy;
            float p    = fmaf(Sx, Sx, Sy * Sy);
            float a1   = fmaf(2.0f, sxsy, C1N2);
            float b1   = p + C1N2;
            float t1   = fmaf(49.0f, Sxy, -sxsy);
            float a2   = fmaf(KA, t1, C2N2);
            float qq   = Sxx + Syy;
            float t2   = fmaf(49.0f, qq, -p);
            float b2   = fmaf(KB, t2, C2N2);
            float num  = a1 * a2;
            float den  = b1 * b2;
            float S    = num * __builtin_amdgcn_rcpf(den);
            accS += (8 * s + m < OUTW) ? S : 0.0f;
        }
        __syncthreads();   // reads done before next iteration's writes
    }

    // reduce: wave shuffle, then 2 partials via LDS, one atomic per block
#pragma unroll
    for (int off = 32; off > 0; off >>= 1)
        accS += __shfl_down(accS, off, 64);
    __shared__ float wsum[2];
    if (s == 0) wsum[wv] = accS;
    __syncthreads();
    if (t == 0) atomicAdd(acc, wsum[0] + wsum[1]);
}

__global__ void ssim_finalize(const float* __restrict__ acc,
                              float* __restrict__ out) {
    if (threadIdx.x == 0) out[0] = 1.0f - acc[0] / TOTAL_OUT;
}

extern "C" void kernel_launch(void* const* d_in, const int* in_sizes, int n_in,
                              void* d_out, int out_size, void* d_ws, size_t ws_size,
                              hipStream_t stream) {
    const float* X = (const float*)d_in[0];
    const float* Y = (const float*)d_in[1];
    float* accum = (float*)d_ws;
    float* out = (float*)d_out;

    hipLaunchKernelGGL(ssim_zero, dim3(1), dim3(64), 0, stream, accum);
    hipLaunchKernelGGL(ssim_main, dim3(NBANDS, NIMG), dim3(128), 0, stream,
                       X, Y, accum);
    hipLaunchKernelGGL(ssim_finalize, dim3(1), dim3(64), 0, stream, accum, out);
}

// Round 3
// 238.793 us; speedup vs baseline: 1.0619x; 1.0407x over previous
//
#include <hip/hip_runtime.h>

// SSIM loss, fused. Round 3: latency attack.
//  - Round-2 data path kept (vertical col sums in regs, re-read retire,
//    stride-12 swizzled LDS, 8-px horizontal strips per lane).
//  - NEW: software pipeline — all 8 global float4 loads for iteration j+2
//    are issued before iteration j's barrier, so they complete during the
//    horizontal phase (~600 cyc). Removes global latency from critical path.
//  - NEW: BAND 46 -> 22 (23 bands x 22 rows = 506 exact): 2208 blocks,
//    8.6/CU submitted, 5 resident (LDS 31 KB cap) = 10 waves/CU.

#define IW    512
#define OUTW  506
#define OUTH  506
#define BAND  22          // output rows per block; 22*23 = 506 exactly
#define NBANDS 23
#define NIMG  96
#define C1N2  0.2401f     // 1e-4 * 49^2
#define C2N2  2.1609f     // 9e-4 * 49^2
#define KA    (49.0f/24.0f)
#define KB    (49.0f/48.0f)
#define TOTAL_OUT 24579456.0f   // 96*506*506

__global__ void ssim_zero(float* acc) {
    if (threadIdx.x == 0) acc[0] = 0.0f;
}

__global__ __launch_bounds__(128) void ssim_main(const float* __restrict__ X,
                                                 const float* __restrict__ Y,
                                                 float* __restrict__ acc) {
    // [2 rows][5 quantities][65 slots * 12 words]; tail slots read-only
    // garbage for lane 63's halo (cols >= 506 masked at accumulate).
    __shared__ float plane[2][5][65 * 12];

    const int t    = threadIdx.x;
    const int band = blockIdx.x;
    const int img  = blockIdx.y;
    const int r0   = band * BAND;
    const float4* X4 = (const float4*)(X + (size_t)img * IW * IW);
    const float4* Y4 = (const float4*)(Y + (size_t)img * IW * IW);
    // thread owns cols 4t..4t+3 ; row stride in float4 units = 128

    float4 s0 = {0,0,0,0}, s1 = {0,0,0,0}, s2 = {0,0,0,0},
           s3 = {0,0,0,0}, s4 = {0,0,0,0};

    // prime with input rows r0 .. r0+5
#pragma unroll
    for (int i = 0; i < 6; ++i) {
        float4 x = X4[(r0 + i) * 128 + t];
        float4 y = Y4[(r0 + i) * 128 + t];
        s0.x += x.x; s0.y += x.y; s0.z += x.z; s0.w += x.w;
        s1.x += y.x; s1.y += y.y; s1.z += y.z; s1.w += y.w;
        s2.x = fmaf(x.x,x.x,s2.x); s2.y = fmaf(x.y,x.y,s2.y);
        s2.z = fmaf(x.z,x.z,s2.z); s2.w = fmaf(x.w,x.w,s2.w);
        s3.x = fmaf(y.x,y.x,s3.x); s3.y = fmaf(y.y,y.y,s3.y);
        s3.z = fmaf(y.z,y.z,s3.z); s3.w = fmaf(y.w,y.w,s3.w);
        s4.x = fmaf(x.x,y.x,s4.x); s4.y = fmaf(x.y,y.y,s4.y);
        s4.z = fmaf(x.z,y.z,s4.z); s4.w = fmaf(x.w,y.w,s4.w);
    }

    const int wslot = 12 * (t >> 1) + 4 * (t & 1);  // float4-aligned word offset
    const int wv = t >> 6;   // wave id (0,1)
    const int s  = t & 63;   // lane
    float accS = 0.0f;

    // prefetch for j = 0: new rows r0+6, r0+7; retire rows r0, r0+1
    float4 pnx[2], pny[2], prx[2], pry[2];
#pragma unroll
    for (int k = 0; k < 2; ++k) {
        pnx[k] = X4[(r0 + 6 + k) * 128 + t];
        pny[k] = Y4[(r0 + 6 + k) * 128 + t];
        prx[k] = X4[(r0 + k) * 128 + t];
        pry[k] = Y4[(r0 + k) * 128 + t];
    }

    for (int j = 0; j < BAND; j += 2) {
#pragma unroll
        for (int k = 0; k < 2; ++k) {
            // add new input row (prefetched)
            float4 x = pnx[k], y = pny[k];
            s0.x += x.x; s0.y += x.y; s0.z += x.z; s0.w += x.w;
            s1.x += y.x; s1.y += y.y; s1.z += y.z; s1.w += y.w;
            s2.x = fmaf(x.x,x.x,s2.x); s2.y = fmaf(x.y,x.y,s2.y);
            s2.z = fmaf(x.z,x.z,s2.z); s2.w = fmaf(x.w,x.w,s2.w);
            s3.x = fmaf(y.x,y.x,s3.x); s3.y = fmaf(y.y,y.y,s3.y);
            s3.z = fmaf(y.z,y.z,s3.z); s3.w = fmaf(y.w,y.w,s3.w);
            s4.x = fmaf(x.x,y.x,s4.x); s4.y = fmaf(x.y,y.y,s4.y);
            s4.z = fmaf(x.z,y.z,s4.z); s4.w = fmaf(x.w,y.w,s4.w);
            // publish column sums (7-row window) for this subrow
            *(float4*)&plane[k][0][wslot] = s0;
            *(float4*)&plane[k][1][wslot] = s1;
            *(float4*)&plane[k][2][wslot] = s2;
            *(float4*)&plane[k][3][wslot] = s3;
            *(float4*)&plane[k][4][wslot] = s4;
            // retire oldest input row (prefetched)
            float4 ox = prx[k], oy = pry[k];
            s0.x -= ox.x; s0.y -= ox.y; s0.z -= ox.z; s0.w -= ox.w;
            s1.x -= oy.x; s1.y -= oy.y; s1.z -= oy.z; s1.w -= oy.w;
            s2.x = fmaf(-ox.x,ox.x,s2.x); s2.y = fmaf(-ox.y,ox.y,s2.y);
            s2.z = fmaf(-ox.z,ox.z,s2.z); s2.w = fmaf(-ox.w,ox.w,s2.w);
            s3.x = fmaf(-oy.x,oy.x,s3.x); s3.y = fmaf(-oy.y,oy.y,s3.y);
            s3.z = fmaf(-oy.z,oy.z,s3.z); s3.w = fmaf(-oy.w,oy.w,s3.w);
            s4.x = fmaf(-ox.x,oy.x,s4.x); s4.y = fmaf(-ox.y,oy.y,s4.y);
            s4.z = fmaf(-ox.z,oy.z,s4.z); s4.w = fmaf(-ox.w,oy.w,s4.w);
        }
        // issue next iteration's 8 loads NOW — they fly during the barrier
        // + horizontal phase and are consumed 2 barriers later.
        if (j + 2 < BAND) {
#pragma unroll
            for (int k = 0; k < 2; ++k) {
                pnx[k] = X4[(r0 + j + 8 + k) * 128 + t];
                pny[k] = Y4[(r0 + j + 8 + k) * 128 + t];
                prx[k] = X4[(r0 + j + 2 + k) * 128 + t];
                pry[k] = Y4[(r0 + j + 2 + k) * 128 + t];
            }
        }
        __syncthreads();   // column sums visible

        // horizontal: wave wv handles output row r0+j+wv; lane s -> cols 8s..8s+7
        float W[5][8];
#pragma unroll
        for (int q = 0; q < 5; ++q) {
            const float* pl = plane[wv][q];
            float4 a  = *(const float4*)(pl + 12 * s);
            float4 b  = *(const float4*)(pl + 12 * s + 4);
            float4 cc = *(const float4*)(pl + 12 * (s + 1));
            float2 dd = *(const float2*)(pl + 12 * (s + 1) + 4);
            float c[14] = {a.x, a.y, a.z, a.w, b.x, b.y, b.z, b.w,
                           cc.x, cc.y, cc.z, cc.w, dd.x, dd.y};
            float Wv = ((c[0] + c[1]) + (c[2] + c[3])) +
                       ((c[4] + c[5]) + c[6]);
            W[q][0] = Wv;
#pragma unroll
            for (int m = 1; m < 8; ++m) {
                Wv += c[m + 6] - c[m - 1];
                W[q][m] = Wv;
            }
        }
#pragma unroll
        for (int m = 0; m < 8; ++m) {
            float Sx = W[0][m], Sy = W[1][m];
            float Sxx = W[2][m], Syy = W[3][m], Sxy = W[4][m];
            float sxsy = Sx * Sy;
            float p    = fmaf(Sx, Sx, Sy * Sy);
            float a1   = fmaf(2.0f, sxsy, C1N2);
            float b1   = p + C1N2;
            float t1   = fmaf(49.0f, Sxy, -sxsy);
            float a2   = fmaf(KA, t1, C2N2);
            float qq   = Sxx + Syy;
            float t2   = fmaf(49.0f, qq, -p);
            float b2   = fmaf(KB, t2, C2N2);
            float num  = a1 * a2;
            float den  = b1 * b2;
            float S    = num * __builtin_amdgcn_rcpf(den);
            accS += (8 * s + m < OUTW) ? S : 0.0f;
        }
        __syncthreads();   // reads done before next iteration's writes
    }

    // reduce: wave shuffle, then 2 partials via LDS, one atomic per block
#pragma unroll
    for (int off = 32; off > 0; off >>= 1)
        accS += __shfl_down(accS, off, 64);
    __shared__ float wsum[2];
    if (s == 0) wsum[wv] = accS;
    __syncthreads();
    if (t == 0) atomicAdd(acc, wsum[0] + wsum[1]);
}

__global__ void ssim_finalize(const float* __restrict__ acc,
                              float* __restrict__ out) {
    if (threadIdx.x == 0) out[0] = 1.0f - acc[0] / TOTAL_OUT;
}

extern "C" void kernel_launch(void* const* d_in, const int* in_sizes, int n_in,
                              void* d_out, int out_size, void* d_ws, size_t ws_size,
                              hipStream_t stream) {
    const float* X = (const float*)d_in[0];
    const float* Y = (const float*)d_in[1];
    float* accum = (float*)d_ws;
    float* out = (float*)d_out;

    hipLaunchKernelGGL(ssim_zero, dim3(1), dim3(64), 0, stream, accum);
    hipLaunchKernelGGL(ssim_main, dim3(NBANDS, NIMG), dim3(128), 0, stream,
                       X, Y, accum);
    hipLaunchKernelGGL(ssim_finalize, dim3(1), dim3(64), 0, stream, accum, out);
}